// Round 4
// baseline (128.978 us; speedup 1.0000x reference)
//
#include <hip/hip_runtime.h>
#include <math.h>

#define PP 4096

typedef __attribute__((ext_vector_type(8))) short short8;
typedef __attribute__((ext_vector_type(4))) short short4v;
typedef __attribute__((ext_vector_type(4))) float float4v;

__device__ __forceinline__ short f2bf(float f) {
    union { float f; unsigned u; } v; v.f = f;
    unsigned r = v.u + 0x7FFFu + ((v.u >> 16) & 1u);
    return (short)(r >> 16);
}

// 16x16x16 bf16 MFMA: prefer native K=16; fall back to zero-padded K=32.
#if __has_builtin(__builtin_amdgcn_mfma_f32_16x16x16bf16_1k)
__device__ __forceinline__ float4v mfma16(short4v a, short4v b, float4v c) {
    return __builtin_amdgcn_mfma_f32_16x16x16bf16_1k(a, b, c, 0, 0, 0);
}
#else
__device__ __forceinline__ float4v mfma16(short4v a, short4v b, float4v c) {
    // zero-pad high half of each quad's k-range: k32 = quad*8 + (0..3) carries
    // the K=16 values, (4..7) zero -> identical contraction.
    short8 a8 = {a[0], a[1], a[2], a[3], 0, 0, 0, 0};
    short8 b8 = {b[0], b[1], b[2], b[3], 0, 0, 0, 0};
    return __builtin_amdgcn_mfma_f32_16x16x32_bf16(a8, b8, c, 0, 0, 0);
}
#endif

// ---------------------------------------------------------------------------
// Kernel 1: q/k/v projections -> bf16.
//   q16, k16: [B, P, 16] bf16 (q pre-scaled by log2e)
//   v_a: x16-A-fragment swizzle: [b][p/16][c/16][quad_p*16 + c%16][p%4]
// grid = B * (P/64) = 256 blocks, 256 threads.
// ---------------------------------------------------------------------------
__global__ __launch_bounds__(256) void qkv_kernel(
    const float* __restrict__ ftr, const float* __restrict__ wq, const float* __restrict__ bq,
    const float* __restrict__ wk, const float* __restrict__ bk,
    const float* __restrict__ wv, const float* __restrict__ bv,
    short* __restrict__ q16, short* __restrict__ k16, short* __restrict__ v_a)
{
    __shared__ float xs[64][68] __attribute__((aligned(16)));
    __shared__ float wvs[64][68] __attribute__((aligned(16)));
    __shared__ float wq_t[64][20] __attribute__((aligned(16)));
    __shared__ float wk_t[64][20] __attribute__((aligned(16)));

    const int b  = blockIdx.x >> 6;
    const int p0 = (blockIdx.x & 63) << 6;
    const int tid = threadIdx.x;

    for (int idx = tid; idx < 1024; idx += 256) {
        int c = idx >> 4, j4 = (idx & 15) << 2;
        *(float4*)&xs[c][j4] = *(const float4*)(ftr + ((size_t)(b * 64 + c)) * PP + p0 + j4);
    }
    for (int idx = tid; idx < 1024; idx += 256) {
        int r = idx >> 4, j4 = (idx & 15) << 2;
        *(float4*)&wvs[r][j4] = *(const float4*)(wv + r * 64 + j4);
    }
    for (int idx = tid; idx < 1024; idx += 256) {
        int o = idx >> 6, c2 = idx & 63;
        wq_t[c2][o] = wq[idx];
        wk_t[c2][o] = wk[idx];
    }
    __syncthreads();

    // ---- v -> x16 A-fragment layout ----
    {
        const int wg = tid >> 6, qd = (tid >> 4) & 3, cc = tid & 15;
        const int c = wg * 16 + cc;
        const float bvc = bv[c];
        #pragma unroll
        for (int kt = 0; kt < 2; ++kt) {
            const int col = kt * 32 + qd * 8;
            float a[8] = {0.f,0.f,0.f,0.f,0.f,0.f,0.f,0.f};
            #pragma unroll 8
            for (int c2 = 0; c2 < 64; ++c2) {
                float w = wvs[c][c2];
                float4 xa = *(const float4*)&xs[c2][col];
                float4 xb = *(const float4*)&xs[c2][col + 4];
                a[0] += w * xa.x; a[1] += w * xa.y; a[2] += w * xa.z; a[3] += w * xa.w;
                a[4] += w * xb.x; a[5] += w * xb.y; a[6] += w * xb.z; a[7] += w * xb.w;
            }
            const int ptg = ((p0 + kt * 32) >> 4) + (qd >> 1);
            const int qp0 = (qd & 1) * 2;
            #pragma unroll
            for (int h = 0; h < 2; ++h) {
                short4v pv;
                #pragma unroll
                for (int j = 0; j < 4; ++j) pv[j] = f2bf(a[h * 4 + j] + bvc);
                *(short4v*)(v_a + ((((size_t)(b * 256 + ptg)) * 4 + wg) * 64 + (qp0 + h) * 16 + cc) * 4) = pv;
            }
        }
    }

    // ---- q/k ----
    {
        const int p_l = tid >> 2, sel = tid & 3;
        const int half = sel & 1, arr = sel >> 1;
        const float* Wtr = arr ? &wk_t[0][0] : &wq_t[0][0];
        float a[8] = {0.f,0.f,0.f,0.f,0.f,0.f,0.f,0.f};
        #pragma unroll 8
        for (int c2 = 0; c2 < 64; ++c2) {
            float x = xs[c2][p_l];
            float4 wA = *(const float4*)(Wtr + c2 * 20 + half * 8);
            float4 wB = *(const float4*)(Wtr + c2 * 20 + half * 8 + 4);
            a[0] += wA.x * x; a[1] += wA.y * x; a[2] += wA.z * x; a[3] += wA.w * x;
            a[4] += wB.x * x; a[5] += wB.y * x; a[6] += wB.z * x; a[7] += wB.w * x;
        }
        const float* bias = arr ? bk : bq;
        const float scl = arr ? 1.0f : 1.4426950408889634f;
        short8 pq;
        #pragma unroll
        for (int oo = 0; oo < 8; ++oo)
            pq[oo] = f2bf((a[oo] + bias[half * 8 + oo]) * scl);
        short* dst = (arr ? k16 : q16) + (((size_t)(b * PP + p0 + p_l)) << 4) + half * 8;
        *(short8*)dst = pq;
    }
}

// ---------------------------------------------------------------------------
// Kernel 2: MFMA flash attention, softmax over p. No LDS in main loop:
// score C-frag == x16 B-frag layout, so exp2'd scores feed PV directly.
// l-sums via ones-A MFMA. Block = 64 q' (4 n-tiles), 8 waves x p-eighth.
// grid = B * 64 = 256 blocks, 512 threads.
// ---------------------------------------------------------------------------
__global__ __launch_bounds__(512, 2) void attn_kernel(
    const short* __restrict__ q16, const short* __restrict__ k16,
    const short* __restrict__ v_a,
    const float* __restrict__ ftr, const float* __restrict__ delta,
    float* __restrict__ out, float* __restrict__ psum, float* __restrict__ pmax)
{
    __shared__ float Obuf[8][16][66];
    __shared__ float lb[8][64];
    __shared__ float lfin[64];

    const int b    = blockIdx.x >> 6;
    const int qblk = blockIdx.x & 63;
    const int q0   = qblk << 6;
    const int tid  = threadIdx.x;
    const int lane = tid & 63;
    const int n    = lane & 15;
    const int quad = lane >> 4;
    const int ph   = tid >> 6;

    const float4v zf4 = {0.f, 0.f, 0.f, 0.f};
    const short4v ones = {0x3F80, 0x3F80, 0x3F80, 0x3F80};  // bf16 1.0 x4

    // K B-frags (persistent): B[k=c=quad*4+j][n=q']
    short4v bkf[4];
    #pragma unroll
    for (int nt = 0; nt < 4; ++nt)
        bkf[nt] = *(const short4v*)(k16 + ((size_t)(b * PP + q0 + nt * 16 + n) << 4) + quad * 4);

    const short* qrow = q16 + ((size_t)(b * PP + n) << 4) + quad * 4;
    const short* vrow = v_a + (size_t)b * 262144 + lane * 4;

    float4v acc[4][4], lacc[4];
    #pragma unroll
    for (int mt = 0; mt < 4; ++mt)
        #pragma unroll
        for (int nt = 0; nt < 4; ++nt) acc[mt][nt] = zf4;
    #pragma unroll
    for (int nt = 0; nt < 4; ++nt) lacc[nt] = zf4;

    const int pt0 = ph * 512;
    for (int it = 0; it < 8; ++it) {
        const int pt = pt0 + it * 64;
        const int pti = pt >> 4;

        // Q A-frags (4 p-tiles) and V A-frags (4 ksteps x 4 c-tiles)
        short4v aq[4];
        #pragma unroll
        for (int f = 0; f < 4; ++f)
            aq[f] = *(const short4v*)(qrow + (size_t)(pt + f * 16) * 16);
        short4v va[4][4];
        #pragma unroll
        for (int f = 0; f < 4; ++f)
            #pragma unroll
            for (int mt = 0; mt < 4; ++mt)
                va[f][mt] = *(const short4v*)(vrow + (size_t)((pti + f) * 4 + mt) * 256);

        // scores one f-step ahead of exp/PV
        float4v sf_c[4], sf_n[4];
        #pragma unroll
        for (int nt = 0; nt < 4; ++nt)
            sf_c[nt] = mfma16(aq[0], bkf[nt], zf4);

        #pragma unroll
        for (int f = 0; f < 4; ++f) {
            if (f < 3) {
                #pragma unroll
                for (int nt = 0; nt < 4; ++nt)
                    sf_n[nt] = mfma16(aq[f + 1], bkf[nt], zf4);
            }
            short4v w[4];
            #pragma unroll
            for (int nt = 0; nt < 4; ++nt) {
                float w0 = __builtin_amdgcn_exp2f(sf_c[nt][0]);
                float w1 = __builtin_amdgcn_exp2f(sf_c[nt][1]);
                float w2 = __builtin_amdgcn_exp2f(sf_c[nt][2]);
                float w3 = __builtin_amdgcn_exp2f(sf_c[nt][3]);
                union { uint2 u; short4v s; } cv;
                cv.u.x = __builtin_amdgcn_perm(__float_as_uint(w1), __float_as_uint(w0), 0x07060302u);
                cv.u.y = __builtin_amdgcn_perm(__float_as_uint(w3), __float_as_uint(w2), 0x07060302u);
                w[nt] = cv.s;
            }
            #pragma unroll
            for (int nt = 0; nt < 4; ++nt)
                lacc[nt] = mfma16(ones, w[nt], lacc[nt]);
            #pragma unroll
            for (int mt = 0; mt < 4; ++mt)
                #pragma unroll
                for (int nt = 0; nt < 4; ++nt)
                    acc[mt][nt] = mfma16(va[f][mt], w[nt], acc[mt][nt]);
            #pragma unroll
            for (int nt = 0; nt < 4; ++nt) sf_c[nt] = sf_n[nt];
        }
    }

    // ---- epilogue ----
    if (quad == 0) {
        #pragma unroll
        for (int nt = 0; nt < 4; ++nt)
            lb[ph][nt * 16 + n] = lacc[nt][0];   // D rows replicated for ones-A
    }
    __syncthreads();
    if (tid < 64) {
        float s = 0.f;
        #pragma unroll
        for (int p8 = 0; p8 < 8; ++p8) s += lb[p8][tid];
        lfin[tid] = delta[0] / s;
    }
    __syncthreads();

    const int c_l = tid >> 5;          // 0..15
    const int q2  = (tid & 31) * 2;    // 0,2,..,62
    #pragma unroll
    for (int mt = 0; mt < 4; ++mt) {
        #pragma unroll
        for (int nt = 0; nt < 4; ++nt)
            #pragma unroll
            for (int i = 0; i < 4; ++i)
                Obuf[ph][quad * 4 + i][nt * 16 + n] = acc[mt][nt][i];
        __syncthreads();
        const int c = mt * 16 + c_l;
        float o0 = 0.f, o1 = 0.f;
        #pragma unroll
        for (int p8 = 0; p8 < 8; ++p8) {
            o0 += Obuf[p8][c_l][q2];
            o1 += Obuf[p8][c_l][q2 + 1];
        }
        const size_t g = ((size_t)(b * 64 + c)) * PP + q0 + q2;
        float2 fv = *(const float2*)(ftr + g);
        o0 = o0 * lfin[q2]     + fv.x;
        o1 = o1 * lfin[q2 + 1] + fv.y;
        float2 ov; ov.x = o0; ov.y = o1;
        *(float2*)(out + g) = ov;
        float s = o0 + o1, m = fmaxf(o0, o1);
        s += __shfl_xor(s, 1); s += __shfl_xor(s, 2);
        s += __shfl_xor(s, 4); s += __shfl_xor(s, 8); s += __shfl_xor(s, 16);
        m = fmaxf(m, __shfl_xor(m, 1)); m = fmaxf(m, __shfl_xor(m, 2));
        m = fmaxf(m, __shfl_xor(m, 4)); m = fmaxf(m, __shfl_xor(m, 8));
        m = fmaxf(m, __shfl_xor(m, 16));
        if ((tid & 31) == 0) {
            psum[((size_t)(b * 64) + qblk) * 64 + c] = s;
            pmax[((size_t)(b * 64) + qblk) * 64 + c] = m;
        }
        __syncthreads();
    }
}

// ---------------------------------------------------------------------------
// Kernel 3: reduce stats partials + SE MLP gate. grid = B blocks, 256 thr.
// ---------------------------------------------------------------------------
__global__ __launch_bounds__(256) void reduce_gate_kernel(
    const float* __restrict__ psum, const float* __restrict__ pmax,
    const float* __restrict__ w_avg1, const float* __restrict__ w_avg2,
    const float* __restrict__ w_max1, const float* __restrict__ w_max2,
    float* __restrict__ gate)
{
    const int b = blockIdx.x, t = threadIdx.x;
    const int c = t & 63, ch = t >> 6;
    float s = 0.f, m = -3.4e38f;
    for (int i = 0; i < 16; ++i) {
        const int qb = ch * 16 + i;
        s += psum[((size_t)(b * 64) + qb) * 64 + c];
        m = fmaxf(m, pmax[((size_t)(b * 64) + qb) * 64 + c]);
    }
    __shared__ float ss[4][64], sm[4][64], fa[64], fm[64], ha[16], hm[16];
    ss[ch][c] = s; sm[ch][c] = m;
    __syncthreads();
    if (t < 64) {
        fa[t] = (ss[0][t] + ss[1][t] + ss[2][t] + ss[3][t]) * (1.f / 4096.f);
        fm[t] = fmaxf(fmaxf(sm[0][t], sm[1][t]), fmaxf(sm[2][t], sm[3][t]));
    }
    __syncthreads();
    if (t < 16) {
        float a = 0.f;
        for (int cc = 0; cc < 64; ++cc) a += fa[cc] * w_avg1[t * 64 + cc];
        ha[t] = fmaxf(a, 0.f);
    } else if (t < 32) {
        float a = 0.f;
        for (int cc = 0; cc < 64; ++cc) a += fm[cc] * w_max1[(t - 16) * 64 + cc];
        hm[t - 16] = fmaxf(a, 0.f);
    }
    __syncthreads();
    if (t < 64) {
        float a = 0.f, mm = 0.f;
        #pragma unroll
        for (int i = 0; i < 16; ++i) {
            a  += ha[i] * w_avg2[t * 16 + i];
            mm += hm[i] * w_max2[t * 16 + i];
        }
        gate[b * 64 + t] = 1.f / (1.f + expf(-(a + mm)));
    }
}

// ---------------------------------------------------------------------------
// Kernel 4: in-place gate multiply, float4. grid = 1024 blocks.
// ---------------------------------------------------------------------------
__global__ __launch_bounds__(256) void mul_kernel(
    float* __restrict__ out, const float* __restrict__ gate)
{
    const float g = gate[blockIdx.x >> 2];
    const size_t e = ((size_t)blockIdx.x * 256 + threadIdx.x) * 4;
    float4 v = *(const float4*)(out + e);
    v.x *= g; v.y *= g; v.z *= g; v.w *= g;
    *(float4*)(out + e) = v;
}

// ---------------------------------------------------------------------------
extern "C" void kernel_launch(void* const* d_in, const int* in_sizes, int n_in,
                              void* d_out, int out_size, void* d_ws, size_t ws_size,
                              hipStream_t stream)
{
    const float* ftr    = (const float*)d_in[0];
    const float* wq     = (const float*)d_in[1];
    const float* bq     = (const float*)d_in[2];
    const float* wk     = (const float*)d_in[3];
    const float* bk     = (const float*)d_in[4];
    const float* wv     = (const float*)d_in[5];
    const float* bv     = (const float*)d_in[6];
    const float* delta  = (const float*)d_in[7];
    const float* w_avg1 = (const float*)d_in[8];
    const float* w_avg2 = (const float*)d_in[9];
    const float* w_max1 = (const float*)d_in[10];
    const float* w_max2 = (const float*)d_in[11];
    float* out = (float*)d_out;

    short* wsS  = (short*)d_ws;
    short* q16  = wsS;                 // 512 KB
    short* k16  = wsS + 262144;        // 512 KB
    short* v_a  = wsS + 524288;        // 2 MB
    float* fbase = (float*)(wsS + 1572864);
    float* psum = fbase;               // 4*64*64 = 16384 floats
    float* pmax = fbase + 16384;
    float* gate = fbase + 32768;

    qkv_kernel<<<256, 256, 0, stream>>>(ftr, wq, bq, wk, bk, wv, bv, q16, k16, v_a);
    attn_kernel<<<256, 512, 0, stream>>>(q16, k16, v_a, ftr, delta, out, psum, pmax);
    reduce_gate_kernel<<<4, 256, 0, stream>>>(psum, pmax, w_avg1, w_avg2, w_max1, w_max2, gate);
    mul_kernel<<<1024, 256, 0, stream>>>(out, gate);
}

// Round 5
// 128.500 us; speedup vs baseline: 1.0037x; 1.0037x over previous
//
#include <hip/hip_runtime.h>
#include <math.h>

#define PP 4096

typedef __attribute__((ext_vector_type(8))) short short8;
typedef __attribute__((ext_vector_type(4))) short short4v;
typedef __attribute__((ext_vector_type(4))) float float4v;

__device__ __forceinline__ short f2bf(float f) {
    union { float f; unsigned u; } v; v.f = f;
    unsigned r = v.u + 0x7FFFu + ((v.u >> 16) & 1u);
    return (short)(r >> 16);
}

// 16x16x16 bf16 MFMA: prefer native K=16; fall back to zero-padded K=32.
#if __has_builtin(__builtin_amdgcn_mfma_f32_16x16x16bf16_1k)
__device__ __forceinline__ float4v mfma16(short4v a, short4v b, float4v c) {
    return __builtin_amdgcn_mfma_f32_16x16x16bf16_1k(a, b, c, 0, 0, 0);
}
#else
__device__ __forceinline__ float4v mfma16(short4v a, short4v b, float4v c) {
    short8 a8 = {a[0], a[1], a[2], a[3], 0, 0, 0, 0};
    short8 b8 = {b[0], b[1], b[2], b[3], 0, 0, 0, 0};
    return __builtin_amdgcn_mfma_f32_16x16x32_bf16(a8, b8, c, 0, 0, 0);
}
#endif

// ---------------------------------------------------------------------------
// Kernel 1: q/k/v projections -> bf16.
//   q16, k16: [B, P, 16] bf16 (q pre-scaled by log2e)
//   v_a: x16-A-fragment swizzle: [b][p/16][c/16][lane=quad_p*16 + c%16][p%4]
// grid = B * (P/32) = 512 blocks (2 blocks/CU), 256 threads.
// ---------------------------------------------------------------------------
__global__ __launch_bounds__(256) void qkv_kernel(
    const float* __restrict__ ftr, const float* __restrict__ wq, const float* __restrict__ bq,
    const float* __restrict__ wk, const float* __restrict__ bk,
    const float* __restrict__ wv, const float* __restrict__ bv,
    short* __restrict__ q16, short* __restrict__ k16, short* __restrict__ v_a)
{
    __shared__ float xs[64][36] __attribute__((aligned(16)));    // x[c][p-local 0..31]
    __shared__ float wvs[64][68] __attribute__((aligned(16)));
    __shared__ float wq_t[64][20] __attribute__((aligned(16)));  // wq^T[c2][o]
    __shared__ float wk_t[64][20] __attribute__((aligned(16)));

    const int b  = blockIdx.x >> 7;
    const int p0 = (blockIdx.x & 127) << 5;
    const int tid = threadIdx.x;

    for (int idx = tid; idx < 512; idx += 256) {    // ftr tile, float4
        int c = idx >> 3, j4 = (idx & 7) << 2;
        *(float4*)&xs[c][j4] = *(const float4*)(ftr + ((size_t)(b * 64 + c)) * PP + p0 + j4);
    }
    for (int idx = tid; idx < 1024; idx += 256) {   // wv, float4
        int r = idx >> 4, j4 = (idx & 15) << 2;
        *(float4*)&wvs[r][j4] = *(const float4*)(wv + r * 64 + j4);
    }
    for (int idx = tid; idx < 1024; idx += 256) {   // wq/wk transposed
        int o = idx >> 6, c2 = idx & 63;
        wq_t[c2][o] = wq[idx];
        wk_t[c2][o] = wk[idx];
    }
    __syncthreads();

    // ---- v -> x16 A-fragment layout (8 p's of one c per thread) ----
    {
        const int wg = tid >> 6, qd = (tid >> 4) & 3, cc = tid & 15;
        const int c = wg * 16 + cc;
        const float bvc = bv[c];
        const int col = qd * 8;
        float a[8] = {0.f,0.f,0.f,0.f,0.f,0.f,0.f,0.f};
        #pragma unroll 8
        for (int c2 = 0; c2 < 64; ++c2) {
            float w = wvs[c][c2];
            float4 xa = *(const float4*)&xs[c2][col];
            float4 xb = *(const float4*)&xs[c2][col + 4];
            a[0] += w * xa.x; a[1] += w * xa.y; a[2] += w * xa.z; a[3] += w * xa.w;
            a[4] += w * xb.x; a[5] += w * xb.y; a[6] += w * xb.z; a[7] += w * xb.w;
        }
        const int ptg = (p0 >> 4) + (qd >> 1);
        const int qp0 = (qd & 1) * 2;
        #pragma unroll
        for (int h = 0; h < 2; ++h) {
            short4v pv;
            #pragma unroll
            for (int j = 0; j < 4; ++j) pv[j] = f2bf(a[h * 4 + j] + bvc);
            *(short4v*)(v_a + ((((size_t)(b * 256 + ptg)) * 4 + wg) * 64 + (qp0 + h) * 16 + cc) * 4) = pv;
        }
    }

    // ---- q/k: (p_l, arr, half, c2-half) per thread; pair-combine via shfl ----
    {
        const int p_l = tid >> 3, sel = tid & 7;
        const int ch = sel & 1, half = (sel >> 1) & 1, arr = sel >> 2;
        const float* Wtr = arr ? &wk_t[0][0] : &wq_t[0][0];
        float a[8] = {0.f,0.f,0.f,0.f,0.f,0.f,0.f,0.f};
        const int c2lo = ch * 32;
        #pragma unroll 8
        for (int c2i = 0; c2i < 32; ++c2i) {
            const int c2 = c2lo + c2i;
            float x = xs[c2][p_l];
            float4 wA = *(const float4*)(Wtr + c2 * 20 + half * 8);
            float4 wB = *(const float4*)(Wtr + c2 * 20 + half * 8 + 4);
            a[0] += wA.x * x; a[1] += wA.y * x; a[2] += wA.z * x; a[3] += wA.w * x;
            a[4] += wB.x * x; a[5] += wB.y * x; a[6] += wB.z * x; a[7] += wB.w * x;
        }
        #pragma unroll
        for (int oo = 0; oo < 8; ++oo) a[oo] += __shfl_xor(a[oo], 1);
        if (ch == 0) {
            const float* bias = arr ? bk : bq;
            const float scl = arr ? 1.0f : 1.4426950408889634f;
            short8 pq;
            #pragma unroll
            for (int oo = 0; oo < 8; ++oo)
                pq[oo] = f2bf((a[oo] + bias[half * 8 + oo]) * scl);
            short* dst = (arr ? k16 : q16) + (((size_t)(b * PP + p0 + p_l)) << 4) + half * 8;
            *(short8*)dst = pq;
        }
    }
}

// ---------------------------------------------------------------------------
// Kernel 2: MFMA flash attention, softmax over p. x16 direct C->B feed
// (no LDS in main loop). Block = 32 q' (2 n-tiles), 8 waves x p-eighth.
// grid = B * 128 = 512 blocks (2 blocks/CU), 512 threads, <=128 VGPR.
// ---------------------------------------------------------------------------
__global__ __launch_bounds__(512, 4) void attn_kernel(
    const short* __restrict__ q16, const short* __restrict__ k16,
    const short* __restrict__ v_a,
    const float* __restrict__ ftr, const float* __restrict__ delta,
    float* __restrict__ out, float* __restrict__ psum, float* __restrict__ pmax)
{
    __shared__ float Obuf[8][16][34];
    __shared__ float lb[8][32];
    __shared__ float lfin[32];

    const int b    = blockIdx.x >> 7;
    const int qblk = blockIdx.x & 127;
    const int q0   = qblk << 5;
    const int tid  = threadIdx.x;
    const int lane = tid & 63;
    const int n    = lane & 15;
    const int quad = lane >> 4;
    const int ph   = tid >> 6;

    const float4v zf4 = {0.f, 0.f, 0.f, 0.f};

    // K B-frags (persistent): B[k=c=quad*4+j][n=q']
    short4v bkf[2];
    #pragma unroll
    for (int nt = 0; nt < 2; ++nt)
        bkf[nt] = *(const short4v*)(k16 + ((size_t)(b * PP + q0 + nt * 16 + n) << 4) + quad * 4);

    const short* qrow = q16 + ((size_t)(b * PP + n) << 4) + quad * 4;
    const short* vrow = v_a + (size_t)b * 262144 + lane * 4;

    float4v acc[4][2];
    #pragma unroll
    for (int mt = 0; mt < 4; ++mt)
        #pragma unroll
        for (int nt = 0; nt < 2; ++nt) acc[mt][nt] = zf4;
    float lsum[2] = {0.f, 0.f};

    const int pt0 = ph * 512;
    #pragma unroll 2
    for (int it = 0; it < 8; ++it) {
        const int pt = pt0 + it * 64;
        const int pti = pt >> 4;

        // Q A-frags (4 p-tiles) and V A-frags (4 ksteps x 4 c-tiles)
        short4v aq[4];
        #pragma unroll
        for (int f = 0; f < 4; ++f)
            aq[f] = *(const short4v*)(qrow + (size_t)(pt + f * 16) * 16);
        short4v va[4][4];
        #pragma unroll
        for (int f = 0; f < 4; ++f)
            #pragma unroll
            for (int mt = 0; mt < 4; ++mt)
                va[f][mt] = *(const short4v*)(vrow + (size_t)((pti + f) * 4 + mt) * 256);

        // scores one f-step ahead of exp/PV
        float4v sf_c[2], sf_n[2];
        #pragma unroll
        for (int nt = 0; nt < 2; ++nt)
            sf_c[nt] = mfma16(aq[0], bkf[nt], zf4);

        #pragma unroll
        for (int f = 0; f < 4; ++f) {
            if (f < 3) {
                #pragma unroll
                for (int nt = 0; nt < 2; ++nt)
                    sf_n[nt] = mfma16(aq[f + 1], bkf[nt], zf4);
            }
            short4v w[2];
            #pragma unroll
            for (int nt = 0; nt < 2; ++nt) {
                float w0 = __builtin_amdgcn_exp2f(sf_c[nt][0]);
                float w1 = __builtin_amdgcn_exp2f(sf_c[nt][1]);
                float w2 = __builtin_amdgcn_exp2f(sf_c[nt][2]);
                float w3 = __builtin_amdgcn_exp2f(sf_c[nt][3]);
                lsum[nt] += (w0 + w1) + (w2 + w3);
                union { uint2 u; short4v s; } cv;
                cv.u.x = __builtin_amdgcn_perm(__float_as_uint(w1), __float_as_uint(w0), 0x07060302u);
                cv.u.y = __builtin_amdgcn_perm(__float_as_uint(w3), __float_as_uint(w2), 0x07060302u);
                w[nt] = cv.s;
            }
            #pragma unroll
            for (int mt = 0; mt < 4; ++mt)
                #pragma unroll
                for (int nt = 0; nt < 2; ++nt)
                    acc[mt][nt] = mfma16(va[f][mt], w[nt], acc[mt][nt]);
            #pragma unroll
            for (int nt = 0; nt < 2; ++nt) sf_c[nt] = sf_n[nt];
        }
    }

    // ---- epilogue ----
    lsum[0] += __shfl_xor(lsum[0], 16); lsum[0] += __shfl_xor(lsum[0], 32);
    lsum[1] += __shfl_xor(lsum[1], 16); lsum[1] += __shfl_xor(lsum[1], 32);
    if (quad == 0) {
        lb[ph][n]      = lsum[0];
        lb[ph][16 + n] = lsum[1];
    }
    __syncthreads();
    if (tid < 32) {
        float s = 0.f;
        #pragma unroll
        for (int p8 = 0; p8 < 8; ++p8) s += lb[p8][tid];
        lfin[tid] = delta[0] / s;
    }
    __syncthreads();

    const int c_l = tid >> 5;          // 0..15
    const int q   = tid & 31;          // 0..31
    #pragma unroll
    for (int mt = 0; mt < 4; ++mt) {
        #pragma unroll
        for (int nt = 0; nt < 2; ++nt)
            #pragma unroll
            for (int i = 0; i < 4; ++i)
                Obuf[ph][quad * 4 + i][nt * 16 + n] = acc[mt][nt][i];
        __syncthreads();
        const int c = mt * 16 + c_l;
        float o = 0.f;
        #pragma unroll
        for (int p8 = 0; p8 < 8; ++p8) o += Obuf[p8][c_l][q];
        const size_t g = ((size_t)(b * 64 + c)) * PP + q0 + q;
        o = o * lfin[q] + ftr[g];
        out[g] = o;
        float s = o, m = o;
        s += __shfl_xor(s, 1); s += __shfl_xor(s, 2);
        s += __shfl_xor(s, 4); s += __shfl_xor(s, 8); s += __shfl_xor(s, 16);
        m = fmaxf(m, __shfl_xor(m, 1)); m = fmaxf(m, __shfl_xor(m, 2));
        m = fmaxf(m, __shfl_xor(m, 4)); m = fmaxf(m, __shfl_xor(m, 8));
        m = fmaxf(m, __shfl_xor(m, 16));
        if (q == 0) {
            psum[((size_t)(b * 128) + qblk) * 64 + c] = s;
            pmax[((size_t)(b * 128) + qblk) * 64 + c] = m;
        }
        __syncthreads();
    }
}

// ---------------------------------------------------------------------------
// Kernel 3: reduce stats partials + SE MLP gate. grid = B blocks, 256 thr.
// ---------------------------------------------------------------------------
__global__ __launch_bounds__(256) void reduce_gate_kernel(
    const float* __restrict__ psum, const float* __restrict__ pmax,
    const float* __restrict__ w_avg1, const float* __restrict__ w_avg2,
    const float* __restrict__ w_max1, const float* __restrict__ w_max2,
    float* __restrict__ gate)
{
    const int b = blockIdx.x, t = threadIdx.x;
    const int c = t & 63, ch = t >> 6;
    float s = 0.f, m = -3.4e38f;
    for (int i = 0; i < 32; ++i) {
        const int qb = ch * 32 + i;
        s += psum[((size_t)(b * 128) + qb) * 64 + c];
        m = fmaxf(m, pmax[((size_t)(b * 128) + qb) * 64 + c]);
    }
    __shared__ float ss[4][64], sm[4][64], fa[64], fm[64], ha[16], hm[16];
    ss[ch][c] = s; sm[ch][c] = m;
    __syncthreads();
    if (t < 64) {
        fa[t] = (ss[0][t] + ss[1][t] + ss[2][t] + ss[3][t]) * (1.f / 4096.f);
        fm[t] = fmaxf(fmaxf(sm[0][t], sm[1][t]), fmaxf(sm[2][t], sm[3][t]));
    }
    __syncthreads();
    if (t < 16) {
        float a = 0.f;
        for (int cc = 0; cc < 64; ++cc) a += fa[cc] * w_avg1[t * 64 + cc];
        ha[t] = fmaxf(a, 0.f);
    } else if (t < 32) {
        float a = 0.f;
        for (int cc = 0; cc < 64; ++cc) a += fm[cc] * w_max1[(t - 16) * 64 + cc];
        hm[t - 16] = fmaxf(a, 0.f);
    }
    __syncthreads();
    if (t < 64) {
        float a = 0.f, mm = 0.f;
        #pragma unroll
        for (int i = 0; i < 16; ++i) {
            a  += ha[i] * w_avg2[t * 16 + i];
            mm += hm[i] * w_max2[t * 16 + i];
        }
        gate[b * 64 + t] = 1.f / (1.f + expf(-(a + mm)));
    }
}

// ---------------------------------------------------------------------------
// Kernel 4: in-place gate multiply, float4. grid = 1024 blocks.
// ---------------------------------------------------------------------------
__global__ __launch_bounds__(256) void mul_kernel(
    float* __restrict__ out, const float* __restrict__ gate)
{
    const float g = gate[blockIdx.x >> 2];
    const size_t e = ((size_t)blockIdx.x * 256 + threadIdx.x) * 4;
    float4 v = *(const float4*)(out + e);
    v.x *= g; v.y *= g; v.z *= g; v.w *= g;
    *(float4*)(out + e) = v;
}

// ---------------------------------------------------------------------------
extern "C" void kernel_launch(void* const* d_in, const int* in_sizes, int n_in,
                              void* d_out, int out_size, void* d_ws, size_t ws_size,
                              hipStream_t stream)
{
    const float* ftr    = (const float*)d_in[0];
    const float* wq     = (const float*)d_in[1];
    const float* bq     = (const float*)d_in[2];
    const float* wk     = (const float*)d_in[3];
    const float* bk     = (const float*)d_in[4];
    const float* wv     = (const float*)d_in[5];
    const float* bv     = (const float*)d_in[6];
    const float* delta  = (const float*)d_in[7];
    const float* w_avg1 = (const float*)d_in[8];
    const float* w_avg2 = (const float*)d_in[9];
    const float* w_max1 = (const float*)d_in[10];
    const float* w_max2 = (const float*)d_in[11];
    float* out = (float*)d_out;

    short* wsS  = (short*)d_ws;
    short* q16  = wsS;                 // 512 KB
    short* k16  = wsS + 262144;        // 512 KB
    short* v_a  = wsS + 524288;        // 2 MB
    float* fbase = (float*)(wsS + 1572864);
    float* psum = fbase;               // 4*128*64 = 32768 floats
    float* pmax = fbase + 32768;
    float* gate = fbase + 65536;

    qkv_kernel<<<512, 256, 0, stream>>>(ftr, wq, bq, wk, bk, wv, bv, q16, k16, v_a);
    attn_kernel<<<512, 512, 0, stream>>>(q16, k16, v_a, ftr, delta, out, psum, pmax);
    reduce_gate_kernel<<<4, 256, 0, stream>>>(psum, pmax, w_avg1, w_avg2, w_max1, w_max2, gate);
    mul_kernel<<<1024, 256, 0, stream>>>(out, gate);
}